// Round 1
// baseline (3392.488 us; speedup 1.0000x reference)
//
#include <hip/hip_runtime.h>

#define D 64

__global__ void init_kernel(const float4* __restrict__ user_w,
                            const float4* __restrict__ item_w,
                            float4* __restrict__ acc,
                            float4* __restrict__ cur,
                            float4* __restrict__ nxt,
                            int n_user4, int n_tot4) {
    int i = blockIdx.x * blockDim.x + threadIdx.x;
    if (i >= n_tot4) return;
    float4 v = (i < n_user4) ? user_w[i] : item_w[i - n_user4];
    acc[i] = v;
    cur[i] = v;
    nxt[i] = make_float4(0.f, 0.f, 0.f, 0.f);
}

// One wave (64 lanes) per edge; lane d handles dim d. Coalesced gather of
// x[src] row + coalesced atomic scatter-add into out[dst] row.
__global__ void spmm_kernel(const int* __restrict__ src,
                            const int* __restrict__ dst,
                            const float* __restrict__ val,
                            const float* __restrict__ x,
                            float* __restrict__ out,
                            int E_) {
    int wid = (int)((blockIdx.x * blockDim.x + threadIdx.x) >> 6);
    int lane = threadIdx.x & 63;
    if (wid >= E_) return;
    int s  = src[wid];
    int d_ = dst[wid];
    float v = val[wid];
    float m = v * x[(long)s * D + lane];
    atomicAdd(&out[(long)d_ * D + lane], m);
}

// acc += nxt; zero old cur (it becomes the scatter target after swap).
__global__ void fuse_kernel(float4* __restrict__ acc,
                            const float4* __restrict__ nxt,
                            float4* __restrict__ cur_zero,
                            int n4) {
    int i = blockIdx.x * blockDim.x + threadIdx.x;
    if (i >= n4) return;
    float4 a = acc[i];
    float4 x = nxt[i];
    a.x += x.x; a.y += x.y; a.z += x.z; a.w += x.w;
    acc[i] = a;
    cur_zero[i] = make_float4(0.f, 0.f, 0.f, 0.f);
}

// One wave per batch element: dot products + reg_loss partials.
__global__ void final_kernel(const float* __restrict__ acc,
                             const float* __restrict__ user_w,
                             const float* __restrict__ item_w,
                             const int* __restrict__ bu,
                             const int* __restrict__ bp,
                             const int* __restrict__ bn,
                             float* __restrict__ out,
                             int U_, int B_) {
    int w = (int)((blockIdx.x * blockDim.x + threadIdx.x) >> 6);
    int lane = threadIdx.x & 63;
    if (w >= B_) return;
    int iu = bu[w], ip = bp[w], in_ = bn[w];
    const float scale = 0.25f;  // 1/(L+1)
    float u = acc[(long)iu * D + lane] * scale;
    float p = acc[(long)(U_ + ip) * D + lane] * scale;
    float g = acc[(long)(U_ + in_) * D + lane] * scale;
    float ps = u * p;
    float ns = u * g;
    float u0 = user_w[(long)iu * D + lane];
    float p0 = item_w[(long)ip * D + lane];
    float n0 = item_w[(long)in_ * D + lane];
    float r = u0 * u0 + p0 * p0 + n0 * n0;
#pragma unroll
    for (int off = 32; off; off >>= 1) {
        ps += __shfl_down(ps, off, 64);
        ns += __shfl_down(ns, off, 64);
        r  += __shfl_down(r, off, 64);
    }
    if (lane == 0) {
        out[w] = ps;
        out[B_ + w] = ns;
        atomicAdd(&out[2 * B_], r);
    }
}

extern "C" void kernel_launch(void* const* d_in, const int* in_sizes, int n_in,
                              void* d_out, int out_size, void* d_ws, size_t ws_size,
                              hipStream_t stream) {
    const int*   edge_src = (const int*)d_in[0];
    const int*   edge_dst = (const int*)d_in[1];
    const float* edge_val = (const float*)d_in[2];
    const float* user_w   = (const float*)d_in[3];
    const float* item_w   = (const float*)d_in[4];
    const int*   bu       = (const int*)d_in[5];
    const int*   bp       = (const int*)d_in[6];
    const int*   bn       = (const int*)d_in[7];

    int E_ = in_sizes[0];
    int U_ = in_sizes[3] / D;
    int I_ = in_sizes[4] / D;
    int B_ = in_sizes[5];
    int N_ = U_ + I_;
    long ND = (long)N_ * D;

    float* acc = (float*)d_ws;
    float* cur = acc + ND;
    float* nxt = cur + ND;
    float* out = (float*)d_out;

    int n4  = (int)(ND / 4);
    int nu4 = U_ * D / 4;

    init_kernel<<<(n4 + 255) / 256, 256, 0, stream>>>(
        (const float4*)user_w, (const float4*)item_w,
        (float4*)acc, (float4*)cur, (float4*)nxt, nu4, n4);

    for (int l = 0; l < 3; ++l) {
        spmm_kernel<<<(E_ + 3) / 4, 256, 0, stream>>>(
            edge_src, edge_dst, edge_val, cur, nxt, E_);
        fuse_kernel<<<(n4 + 255) / 256, 256, 0, stream>>>(
            (float4*)acc, (const float4*)nxt, (float4*)cur, n4);
        float* t = cur; cur = nxt; nxt = t;
    }

    hipMemsetAsync(out + 2 * B_, 0, sizeof(float), stream);
    final_kernel<<<(B_ * 64 + 255) / 256, 256, 0, stream>>>(
        acc, user_w, item_w, bu, bp, bn, out, U_, B_);
}

// Round 2
// 1803.222 us; speedup vs baseline: 1.8813x; 1.8813x over previous
//
#include <hip/hip_runtime.h>

#define D 64

// ---------------- shared epilogue kernels ----------------

__global__ void init2_kernel(const float4* __restrict__ user_w,
                             const float4* __restrict__ item_w,
                             float4* __restrict__ acc,
                             float4* __restrict__ cur,
                             int n_user4, int n_tot4) {
    int i = blockIdx.x * blockDim.x + threadIdx.x;
    if (i >= n_tot4) return;
    float4 v = (i < n_user4) ? user_w[i] : item_w[i - n_user4];
    acc[i] = v;
    cur[i] = v;
}

__global__ void final_kernel(const float* __restrict__ acc,
                             const float* __restrict__ user_w,
                             const float* __restrict__ item_w,
                             const int* __restrict__ bu,
                             const int* __restrict__ bp,
                             const int* __restrict__ bn,
                             float* __restrict__ out,
                             int U_, int B_) {
    int w = (int)((blockIdx.x * blockDim.x + threadIdx.x) >> 6);
    int lane = threadIdx.x & 63;
    if (w >= B_) return;
    int iu = bu[w], ip = bp[w], in_ = bn[w];
    const float scale = 0.25f;  // 1/(L+1)
    float u = acc[(long)iu * D + lane] * scale;
    float p = acc[(long)(U_ + ip) * D + lane] * scale;
    float g = acc[(long)(U_ + in_) * D + lane] * scale;
    float ps = u * p;
    float ns = u * g;
    float u0 = user_w[(long)iu * D + lane];
    float p0 = item_w[(long)ip * D + lane];
    float n0 = item_w[(long)in_ * D + lane];
    float r = u0 * u0 + p0 * p0 + n0 * n0;
#pragma unroll
    for (int off = 32; off; off >>= 1) {
        ps += __shfl_down(ps, off, 64);
        ns += __shfl_down(ns, off, 64);
        r  += __shfl_down(r, off, 64);
    }
    if (lane == 0) {
        out[w] = ps;
        out[B_ + w] = ns;
        atomicAdd(&out[2 * B_], r);
    }
}

// ---------------- CSR build ----------------

__global__ void hist_kernel(const int* __restrict__ dst, int* __restrict__ deg, int E_) {
    int i = blockIdx.x * blockDim.x + threadIdx.x;
    if (i < E_) atomicAdd(&deg[dst[i]], 1);
}

// Single block, 1024 threads: exclusive scan of deg[0..N) -> row_ptr, cur_pos.
__global__ void scan_kernel(const int* __restrict__ deg,
                            int* __restrict__ row_ptr,
                            int* __restrict__ cur_pos, int N_) {
    __shared__ int sh[1024];
    int tid = threadIdx.x;
    int chunk = (N_ + 1023) >> 10;
    int beg = tid * chunk;
    int end = min(beg + chunk, N_);
    int s = 0;
    for (int i = beg; i < end; ++i) s += deg[i];
    sh[tid] = s;
    __syncthreads();
    for (int off = 1; off < 1024; off <<= 1) {
        int v = (tid >= off) ? sh[tid - off] : 0;
        __syncthreads();
        sh[tid] += v;
        __syncthreads();
    }
    int run = (tid > 0) ? sh[tid - 1] : 0;  // exclusive prefix of this chunk
    for (int i = beg; i < end; ++i) {
        row_ptr[i] = run;
        cur_pos[i] = run;
        run += deg[i];
    }
    if (beg < N_ && end == N_) row_ptr[N_] = run;
}

__global__ void scatter_kernel(const int* __restrict__ src,
                               const int* __restrict__ dst,
                               const float* __restrict__ val,
                               int* __restrict__ cur_pos,
                               int2* __restrict__ col_val, int E_) {
    int i = blockIdx.x * blockDim.x + threadIdx.x;
    if (i >= E_) return;
    int p = atomicAdd(&cur_pos[dst[i]], 1);
    col_val[p] = make_int2(src[i], __float_as_int(val[i]));
}

// ---------------- CSR gather SpMM (fused acc update) ----------------

__global__ void spmm_csr_kernel(const int* __restrict__ row_ptr,
                                const int2* __restrict__ col_val,
                                const float* __restrict__ x,
                                float* __restrict__ nxt,
                                float* __restrict__ acc, int N_) {
    int row = (int)((blockIdx.x * blockDim.x + threadIdx.x) >> 6);
    int lane = threadIdx.x & 63;
    if (row >= N_) return;
    int beg = row_ptr[row];
    int end = row_ptr[row + 1];
    float s = 0.f;
    for (int base = beg; base < end; base += 64) {
        int e = base + lane;
        int c = 0;
        float v = 0.f;
        if (e < end) {
            int2 cv = col_val[e];
            c = cv.x;
            v = __int_as_float(cv.y);
        }
        int m = min(64, end - base);
        for (int j = 0; j < m; ++j) {
            int cj = __shfl(c, j, 64);
            float vj = __shfl(v, j, 64);
            s += vj * x[(long)cj * D + lane];
        }
    }
    long o = (long)row * D + lane;
    nxt[o] = s;
    acc[o] += s;
}

// ---------------- fallback (round-1 atomic path) ----------------

__global__ void init_kernel(const float4* __restrict__ user_w,
                            const float4* __restrict__ item_w,
                            float4* __restrict__ acc,
                            float4* __restrict__ cur,
                            float4* __restrict__ nxt,
                            int n_user4, int n_tot4) {
    int i = blockIdx.x * blockDim.x + threadIdx.x;
    if (i >= n_tot4) return;
    float4 v = (i < n_user4) ? user_w[i] : item_w[i - n_user4];
    acc[i] = v;
    cur[i] = v;
    nxt[i] = make_float4(0.f, 0.f, 0.f, 0.f);
}

__global__ void spmm_kernel(const int* __restrict__ src,
                            const int* __restrict__ dst,
                            const float* __restrict__ val,
                            const float* __restrict__ x,
                            float* __restrict__ out,
                            int E_) {
    int wid = (int)((blockIdx.x * blockDim.x + threadIdx.x) >> 6);
    int lane = threadIdx.x & 63;
    if (wid >= E_) return;
    int s = src[wid];
    int d_ = dst[wid];
    float v = val[wid];
    atomicAdd(&out[(long)d_ * D + lane], v * x[(long)s * D + lane]);
}

__global__ void fuse_kernel(float4* __restrict__ acc,
                            const float4* __restrict__ nxt,
                            float4* __restrict__ cur_zero,
                            int n4) {
    int i = blockIdx.x * blockDim.x + threadIdx.x;
    if (i >= n4) return;
    float4 a = acc[i];
    float4 x = nxt[i];
    a.x += x.x; a.y += x.y; a.z += x.z; a.w += x.w;
    acc[i] = a;
    cur_zero[i] = make_float4(0.f, 0.f, 0.f, 0.f);
}

// ---------------- launch ----------------

extern "C" void kernel_launch(void* const* d_in, const int* in_sizes, int n_in,
                              void* d_out, int out_size, void* d_ws, size_t ws_size,
                              hipStream_t stream) {
    const int*   edge_src = (const int*)d_in[0];
    const int*   edge_dst = (const int*)d_in[1];
    const float* edge_val = (const float*)d_in[2];
    const float* user_w   = (const float*)d_in[3];
    const float* item_w   = (const float*)d_in[4];
    const int*   bu       = (const int*)d_in[5];
    const int*   bp       = (const int*)d_in[6];
    const int*   bn       = (const int*)d_in[7];

    int E_ = in_sizes[0];
    int U_ = in_sizes[3] / D;
    int I_ = in_sizes[4] / D;
    int B_ = in_sizes[5];
    int N_ = U_ + I_;
    long ND = (long)N_ * D;

    float* acc = (float*)d_ws;
    float* cur = acc + ND;
    float* nxt = cur + ND;
    float* out = (float*)d_out;

    int n4  = (int)(ND / 4);
    int nu4 = U_ * D / 4;

    // CSR layout after the 3 float buffers
    char* p = (char*)(nxt + ND);
    int2* col_val = (int2*)p;            p += (size_t)E_ * sizeof(int2);
    int*  deg     = (int*)p;             p += (size_t)N_ * sizeof(int);
    int*  row_ptr = (int*)p;             p += (size_t)(N_ + 1) * sizeof(int);
    int*  cur_pos = (int*)p;             p += (size_t)N_ * sizeof(int);
    size_t need = (size_t)(p - (char*)d_ws);

    hipMemsetAsync(out + 2 * B_, 0, sizeof(float), stream);

    if (ws_size >= need) {
        // ---- CSR path ----
        hipMemsetAsync(deg, 0, (size_t)N_ * sizeof(int), stream);
        hist_kernel<<<(E_ + 255) / 256, 256, 0, stream>>>(edge_dst, deg, E_);
        scan_kernel<<<1, 1024, 0, stream>>>(deg, row_ptr, cur_pos, N_);
        scatter_kernel<<<(E_ + 255) / 256, 256, 0, stream>>>(
            edge_src, edge_dst, edge_val, cur_pos, col_val, E_);

        init2_kernel<<<(n4 + 255) / 256, 256, 0, stream>>>(
            (const float4*)user_w, (const float4*)item_w,
            (float4*)acc, (float4*)cur, nu4, n4);

        for (int l = 0; l < 3; ++l) {
            spmm_csr_kernel<<<(N_ + 3) / 4, 256, 0, stream>>>(
                row_ptr, col_val, cur, nxt, acc, N_);
            float* t = cur; cur = nxt; nxt = t;
        }
    } else {
        // ---- fallback: atomic scatter path ----
        init_kernel<<<(n4 + 255) / 256, 256, 0, stream>>>(
            (const float4*)user_w, (const float4*)item_w,
            (float4*)acc, (float4*)cur, (float4*)nxt, nu4, n4);
        for (int l = 0; l < 3; ++l) {
            spmm_kernel<<<(E_ + 3) / 4, 256, 0, stream>>>(
                edge_src, edge_dst, edge_val, cur, nxt, E_);
            fuse_kernel<<<(n4 + 255) / 256, 256, 0, stream>>>(
                (float4*)acc, (const float4*)nxt, (float4*)cur, n4);
            float* t = cur; cur = nxt; nxt = t;
        }
    }

    final_kernel<<<(B_ * 64 + 255) / 256, 256, 0, stream>>>(
        acc, user_w, item_w, bu, bp, bn, out, U_, B_);
}

// Round 3
// 1149.107 us; speedup vs baseline: 2.9523x; 1.5692x over previous
//
#include <hip/hip_runtime.h>

#define D 64

// ---- bf16 helpers (manual, via ushort) ----
static __device__ __forceinline__ unsigned short f2bf(float f) {
    unsigned int u = __float_as_uint(f);
    unsigned int r = (u + 0x7FFFu + ((u >> 16) & 1u)) >> 16;
    return (unsigned short)r;
}
static __device__ __forceinline__ float bf2f(unsigned short b) {
    return __uint_as_float(((unsigned int)b) << 16);
}

// ---------------- init: fp32 acc + bf16 cur ----------------
__global__ void init_kernel(const float4* __restrict__ user_w,
                            const float4* __restrict__ item_w,
                            float4* __restrict__ acc,
                            ushort4* __restrict__ curb,
                            int n_user4, int n_tot4) {
    int i = blockIdx.x * blockDim.x + threadIdx.x;
    if (i >= n_tot4) return;
    float4 v = (i < n_user4) ? user_w[i] : item_w[i - n_user4];
    acc[i] = v;
    ushort4 b;
    b.x = f2bf(v.x); b.y = f2bf(v.y); b.z = f2bf(v.z); b.w = f2bf(v.w);
    curb[i] = b;
}

// ---------------- CSR build ----------------
__global__ void hist_kernel(const int* __restrict__ dst, int* __restrict__ deg, int E_) {
    int i = blockIdx.x * blockDim.x + threadIdx.x;
    if (i < E_) atomicAdd(&deg[dst[i]], 1);
}

// A: per-block partial sums of deg (block = 1024 elems)
__global__ void partial_kernel(const int* __restrict__ deg, int* __restrict__ partial, int N_) {
    __shared__ int sh[1024];
    int tid = threadIdx.x;
    int i = blockIdx.x * 1024 + tid;
    sh[tid] = (i < N_) ? deg[i] : 0;
    __syncthreads();
    for (int off = 512; off; off >>= 1) {
        if (tid < off) sh[tid] += sh[tid + off];
        __syncthreads();
    }
    if (tid == 0) partial[blockIdx.x] = sh[0];
}

// B: single block, exclusive scan of up to 1024 partials (in place)
__global__ void scan_partials_kernel(int* __restrict__ partial, int G_) {
    __shared__ int sh[1024];
    int tid = threadIdx.x;
    int v = (tid < G_) ? partial[tid] : 0;
    sh[tid] = v;
    __syncthreads();
    for (int off = 1; off < 1024; off <<= 1) {
        int t = (tid >= off) ? sh[tid - off] : 0;
        __syncthreads();
        sh[tid] += t;
        __syncthreads();
    }
    if (tid < G_) partial[tid] = sh[tid] - v;  // exclusive
}

// C: block-local scan + global offset -> row_ptr, cur_pos
__global__ void scan_write_kernel(const int* __restrict__ deg,
                                  const int* __restrict__ partial,
                                  int* __restrict__ row_ptr,
                                  int* __restrict__ cur_pos,
                                  int N_, int E_) {
    __shared__ int sh[1024];
    int tid = threadIdx.x;
    int i = blockIdx.x * 1024 + tid;
    int v = (i < N_) ? deg[i] : 0;
    sh[tid] = v;
    __syncthreads();
    for (int off = 1; off < 1024; off <<= 1) {
        int t = (tid >= off) ? sh[tid - off] : 0;
        __syncthreads();
        sh[tid] += t;
        __syncthreads();
    }
    if (i < N_) {
        int excl = sh[tid] - v + partial[blockIdx.x];
        row_ptr[i] = excl;
        cur_pos[i] = excl;
    }
    if (i == N_ - 1 || (i == N_)) row_ptr[N_] = E_;
}

__global__ void scatter_kernel(const int* __restrict__ src,
                               const int* __restrict__ dst,
                               const float* __restrict__ val,
                               int* __restrict__ cur_pos,
                               int2* __restrict__ col_val, int E_) {
    int i = blockIdx.x * blockDim.x + threadIdx.x;
    if (i >= E_) return;
    int p = atomicAdd(&cur_pos[dst[i]], 1);
    col_val[p] = make_int2(src[i], __float_as_int(val[i]));
}

// ---------------- CSR gather SpMM, bf16 rows ----------------
// Wave per row. Lane-halves process 2 edges per step; each half loads the
// full 128B bf16 row (32 lanes x ushort2). acc stays fp32.
__global__ void spmm_csr_kernel(const int* __restrict__ row_ptr,
                                const int2* __restrict__ col_val,
                                const ushort2* __restrict__ xb,
                                ushort2* __restrict__ nxtb,
                                float2* __restrict__ acc, int N_) {
    int row = (int)((blockIdx.x * blockDim.x + threadIdx.x) >> 6);
    int lane = threadIdx.x & 63;
    if (row >= N_) return;
    int half = lane >> 5;
    int lid = lane & 31;
    int beg = row_ptr[row];
    int end = row_ptr[row + 1];
    float sx = 0.f, sy = 0.f;
    for (int base = beg; base < end; base += 64) {
        int e = base + lane;
        int c = 0;
        float v = 0.f;
        if (e < end) {
            int2 cv = col_val[e];
            c = cv.x;
            v = __int_as_float(cv.y);
        }
        int m = min(64, end - base);
        int m2 = (m + 1) & ~1;
        for (int j = 0; j < m2; j += 2) {
            int cj = __shfl(c, j + half, 64);
            float vj = __shfl(v, j + half, 64);
            ushort2 q = xb[(long)cj * 32 + lid];
            sx += vj * bf2f(q.x);
            sy += vj * bf2f(q.y);
        }
    }
    sx += __shfl_xor(sx, 32, 64);
    sy += __shfl_xor(sy, 32, 64);
    if (half == 0) {
        long o = (long)row * 32 + lid;
        ushort2 b;
        b.x = f2bf(sx);
        b.y = f2bf(sy);
        nxtb[o] = b;
        float2 a = acc[o];
        a.x += sx;
        a.y += sy;
        acc[o] = a;
    }
}

// ---------------- epilogue ----------------
__global__ void final_kernel(const float* __restrict__ acc,
                             const float* __restrict__ user_w,
                             const float* __restrict__ item_w,
                             const int* __restrict__ bu,
                             const int* __restrict__ bp,
                             const int* __restrict__ bn,
                             float* __restrict__ out,
                             int U_, int B_) {
    int w = (int)((blockIdx.x * blockDim.x + threadIdx.x) >> 6);
    int lane = threadIdx.x & 63;
    if (w >= B_) return;
    int iu = bu[w], ip = bp[w], in_ = bn[w];
    const float scale = 0.25f;  // 1/(L+1)
    float u = acc[(long)iu * D + lane] * scale;
    float p = acc[(long)(U_ + ip) * D + lane] * scale;
    float g = acc[(long)(U_ + in_) * D + lane] * scale;
    float ps = u * p;
    float ns = u * g;
    float u0 = user_w[(long)iu * D + lane];
    float p0 = item_w[(long)ip * D + lane];
    float n0 = item_w[(long)in_ * D + lane];
    float r = u0 * u0 + p0 * p0 + n0 * n0;
#pragma unroll
    for (int off = 32; off; off >>= 1) {
        ps += __shfl_down(ps, off, 64);
        ns += __shfl_down(ns, off, 64);
        r  += __shfl_down(r, off, 64);
    }
    if (lane == 0) {
        out[w] = ps;
        out[B_ + w] = ns;
        atomicAdd(&out[2 * B_], r);
    }
}

// ---------------- launch ----------------
extern "C" void kernel_launch(void* const* d_in, const int* in_sizes, int n_in,
                              void* d_out, int out_size, void* d_ws, size_t ws_size,
                              hipStream_t stream) {
    const int*   edge_src = (const int*)d_in[0];
    const int*   edge_dst = (const int*)d_in[1];
    const float* edge_val = (const float*)d_in[2];
    const float* user_w   = (const float*)d_in[3];
    const float* item_w   = (const float*)d_in[4];
    const int*   bu       = (const int*)d_in[5];
    const int*   bp       = (const int*)d_in[6];
    const int*   bn       = (const int*)d_in[7];

    int E_ = in_sizes[0];
    int U_ = in_sizes[3] / D;
    int I_ = in_sizes[4] / D;
    int B_ = in_sizes[5];
    int N_ = U_ + I_;
    long ND = (long)N_ * D;

    // workspace layout
    char* p = (char*)d_ws;
    float* acc = (float*)p;              p += (size_t)ND * sizeof(float);
    unsigned short* curb = (unsigned short*)p;  p += (size_t)ND * sizeof(unsigned short);
    unsigned short* nxtb = (unsigned short*)p;  p += (size_t)ND * sizeof(unsigned short);
    int2* col_val = (int2*)p;            p += (size_t)E_ * sizeof(int2);
    int*  deg     = (int*)p;             p += (size_t)N_ * sizeof(int);
    int*  row_ptr = (int*)p;             p += (size_t)(N_ + 1) * sizeof(int);
    int*  cur_pos = (int*)p;             p += (size_t)N_ * sizeof(int);
    int*  partial = (int*)p;             p += 1024 * sizeof(int);
    float* out = (float*)d_out;

    int n4 = (int)(ND / 4);
    int nu4 = U_ * D / 4;
    int G = (N_ + 1023) / 1024;  // <= 1024 required (N_ <= 1M)

    // CSR build
    hipMemsetAsync(deg, 0, (size_t)N_ * sizeof(int), stream);
    hist_kernel<<<(E_ + 255) / 256, 256, 0, stream>>>(edge_dst, deg, E_);
    partial_kernel<<<G, 1024, 0, stream>>>(deg, partial, N_);
    scan_partials_kernel<<<1, 1024, 0, stream>>>(partial, G);
    scan_write_kernel<<<G, 1024, 0, stream>>>(deg, partial, row_ptr, cur_pos, N_, E_);
    scatter_kernel<<<(E_ + 255) / 256, 256, 0, stream>>>(
        edge_src, edge_dst, edge_val, cur_pos, col_val, E_);

    // embeddings init
    init_kernel<<<(n4 + 255) / 256, 256, 0, stream>>>(
        (const float4*)user_w, (const float4*)item_w,
        (float4*)acc, (ushort4*)curb, nu4, n4);

    // propagation
    unsigned short* cb = curb;
    unsigned short* nb = nxtb;
    for (int l = 0; l < 3; ++l) {
        spmm_csr_kernel<<<(N_ + 3) / 4, 256, 0, stream>>>(
            row_ptr, col_val, (const ushort2*)cb, (ushort2*)nb, (float2*)acc, N_);
        unsigned short* t = cb; cb = nb; nb = t;
    }

    // epilogue
    hipMemsetAsync(out + 2 * B_, 0, sizeof(float), stream);
    final_kernel<<<(B_ * 64 + 255) / 256, 256, 0, stream>>>(
        acc, user_w, item_w, bu, bp, bn, out, U_, B_);
}